// Round 3
// baseline (749.989 us; speedup 1.0000x reference)
//
#include <hip/hip_runtime.h>

#define D_MODEL 512
#define SEQ     4096
#define BATCH   4
#define M_TOT   (BATCH*SEQ)   // 16384
#define NT      (SEQ/32)      // 128 key tiles
#define WS_NEEDED ((size_t)2 * M_TOT * D_MODEL * 2)   // node_bf + nodeT_bf: 32 MiB

typedef float  f32x4  __attribute__((ext_vector_type(4)));
typedef __bf16 bf16x8 __attribute__((ext_vector_type(8)));

// lgkm-only barrier: syncs LDS data across waves WITHOUT draining vmcnt,
// so in-flight global_load_lds prefetches survive across it.
#define LGKM_BARRIER() asm volatile("s_waitcnt lgkmcnt(0)\n\ts_barrier" ::: "memory")

union FU { float f; unsigned int u; };
__device__ __forceinline__ unsigned short f_to_bf16(float f) {
    FU c; c.f = f;
    unsigned int r = c.u + 0x7fffu + ((c.u >> 16) & 1u);   // RNE
    return (unsigned short)(r >> 16);
}

// -------- K1: node_bf = relu(x @ W^T + b) (bf16), + transposed copy --------
extern "C" __global__ __launch_bounds__(256) void proj_kernel(
        const float* __restrict__ x, const float* __restrict__ w,
        const float* __restrict__ bias,
        unsigned short* __restrict__ node_bf, unsigned short* __restrict__ nodeT_bf) {
    __shared__ float As[32][68];   // k-major, +4 pad
    __shared__ float Bs[32][68];
    const int tid  = threadIdx.x;
    const int row0 = blockIdx.x * 64;
    const int col0 = blockIdx.y * 64;
    const int m0   = (tid & 15) * 4;
    const int n0   = (tid >> 4) * 4;

    float acc[4][4];
    #pragma unroll
    for (int i = 0; i < 4; ++i)
        #pragma unroll
        for (int j = 0; j < 4; ++j) acc[i][j] = 0.0f;

    for (int kc = 0; kc < D_MODEL; kc += 32) {
        #pragma unroll
        for (int jj = 0; jj < 2; ++jj) {
            int fi = tid + 256*jj;
            int r  = fi >> 3, c4 = (fi & 7) * 4;
            float4 a4 = *(const float4*)(x + (size_t)(row0 + r)*D_MODEL + kc + c4);
            As[c4+0][r] = a4.x; As[c4+1][r] = a4.y; As[c4+2][r] = a4.z; As[c4+3][r] = a4.w;
            float4 b4 = *(const float4*)(w + (size_t)(col0 + r)*D_MODEL + kc + c4);
            Bs[c4+0][r] = b4.x; Bs[c4+1][r] = b4.y; Bs[c4+2][r] = b4.z; Bs[c4+3][r] = b4.w;
        }
        __syncthreads();
        #pragma unroll
        for (int k = 0; k < 32; ++k) {
            float4 a = *(const float4*)&As[k][m0];
            float4 b = *(const float4*)&Bs[k][n0];
            acc[0][0] += a.x*b.x; acc[0][1] += a.x*b.y; acc[0][2] += a.x*b.z; acc[0][3] += a.x*b.w;
            acc[1][0] += a.y*b.x; acc[1][1] += a.y*b.y; acc[1][2] += a.y*b.z; acc[1][3] += a.y*b.w;
            acc[2][0] += a.z*b.x; acc[2][1] += a.z*b.y; acc[2][2] += a.z*b.z; acc[2][3] += a.z*b.w;
            acc[3][0] += a.w*b.x; acc[3][1] += a.w*b.y; acc[3][2] += a.w*b.z; acc[3][3] += a.w*b.w;
        }
        __syncthreads();
    }
    #pragma unroll
    for (int j = 0; j < 4; ++j) {
        float bv = bias[col0 + n0 + j];
        #pragma unroll
        for (int i = 0; i < 4; ++i) {
            float v = acc[i][j] + bv;
            v = v > 0.0f ? v : 0.0f;
            unsigned short us = f_to_bf16(v);
            int row = row0 + m0 + i, col = col0 + n0 + j;
            node_bf[(size_t)row*D_MODEL + col] = us;
            int b = row >> 12, si = row & 4095;
            nodeT_bf[((size_t)(b*D_MODEL + col))*SEQ + si] = us;
        }
    }
}

// -------- K2: flash attention via MFMA, out(fp32) --------
// v4: back to 4 waves (1 wave/SIMD, proven non-binding in v3), but each wave
// is m-blocked over TWO 16-row q-blocks (32 qrows/wave): one LDS B-fragment
// (K or V) feeds 2 MFMAs -> LDS read traffic HALVES (272 -> 136 b128/iter/CU).
// VGPR-heavy (~300: qf 128 + o 128) -> __launch_bounds__(256,1) for the
// 512-VGPR budget at 1 wave/SIMD.
// Wave (qg=wv&1, kh=wv>>1):
//   QK^T: 32 qrows x 16-key half, 16 B-reads / 32 MFMA.
//   PV:   32 qrows x 256-d half,  16 B-reads / 32 MFMA (no O merge).
//   l per-half with shared alpha; summed once at the end.
// Double-buffered K+V via global_load_lds (linear dest + source swizzle, T21),
// lgkm-only mid-iter barriers, single vmcnt-draining __syncthreads per iter.
// LDS: 65536 (Ks) + 65536 (Vt) + 5120 (Ps) + 512 (Sm) = 136704 B
extern "C" __global__ __launch_bounds__(256, 1) void flash_kernel(
        const unsigned short* __restrict__ node,
        const unsigned short* __restrict__ nodeT,
        float* __restrict__ out) {
    __shared__ unsigned short Ks[2][32][512];   // [buf][key][d], chunk ^ (key&7)
    __shared__ unsigned short Vt[2][512][32];   // [buf][d][key], chunk ^ (d&3)
    __shared__ unsigned short Ps[2][32][40];    // [qg][qrow][key], +8 pad
    __shared__ float          Sm[2][2][32];     // [qg][kh][row] exchange buffer
    const int tid  = threadIdx.x;
    const int lane = tid & 63;
    const int wv   = tid >> 6;        // 0..3
    const int qg   = wv & 1;          // 32-row q group
    const int kh   = wv >> 1;         // key half (QK) / d half (PV)
    const int lr   = lane & 15;
    const int quad = lane >> 4;
    const int bb   = blockIdx.y;
    const int q0   = blockIdx.x * 64;

    const unsigned short* nb  = node  + (size_t)bb * SEQ * D_MODEL;
    const unsigned short* ntb = nodeT + (size_t)bb * D_MODEL * SEQ;

    // Q fragments for 2 m-blocks: A[m=lr][k = t*32 + quad*8 + j]
    bf16x8 qf[2][16];
    #pragma unroll
    for (int mb = 0; mb < 2; ++mb) {
        const int qrow = q0 + qg*32 + mb*16 + lr;
        #pragma unroll
        for (int t = 0; t < 16; ++t)
            qf[mb][t] = *reinterpret_cast<const bf16x8*>(&nb[(size_t)qrow*D_MODEL + t*32 + quad*8]);
    }

    f32x4 o[2][16];                   // [mblk][dblk]: 32 qrows x 256 d (own half)
    #pragma unroll
    for (int mb = 0; mb < 2; ++mb)
        #pragma unroll
        for (int n = 0; n < 16; ++n) o[mb][n] = (f32x4){0.f,0.f,0.f,0.f};
    float m_run[2][4] = {{-3.0e38f,-3.0e38f,-3.0e38f,-3.0e38f},
                         {-3.0e38f,-3.0e38f,-3.0e38f,-3.0e38f}};
    float l_run[2][4] = {{0.f,0.f,0.f,0.f},{0.f,0.f,0.f,0.f}};

    const int krow = wv*8;     // this wave stages K rows krow..krow+7
    const int vd0b = wv*128;   // this wave stages V d-rows vd0b..vd0b+127

    // stage tile kt into buffer buf. LDS dest linear; source carries the
    // inverse chunk swizzle (T21).
    auto stage = [&](int kt, int buf) {
        #pragma unroll
        for (int i = 0; i < 8; ++i) {
            int r = krow + i;
            const unsigned short* g = nb + (size_t)(kt*32 + r)*D_MODEL + ((lane ^ (r & 7)) << 3);
            __builtin_amdgcn_global_load_lds(
                (const __attribute__((address_space(1))) unsigned int*)g,
                (__attribute__((address_space(3))) unsigned int*)&Ks[buf][r][0],
                16, 0, 0);
        }
        #pragma unroll
        for (int i = 0; i < 8; ++i) {
            int d0 = vd0b + i*16;
            int d  = d0 + (lane >> 2);
            const unsigned short* g = ntb + (size_t)d*SEQ + kt*32 + ((((lane & 3) ^ (d & 3))) << 3);
            __builtin_amdgcn_global_load_lds(
                (const __attribute__((address_space(1))) unsigned int*)g,
                (__attribute__((address_space(3))) unsigned int*)&Vt[buf][d0][0],
                16, 0, 0);
        }
    };

    stage(0, 0);
    __syncthreads();           // drains vmcnt: tile 0 resident

    const int kxor = lr & 7;   // K read swizzle (row&7 == lr&7)
    const int vxor = lr & 3;   // V read swizzle (d&3   == lr&3)

    for (int kt = 0; kt < NT; ++kt) {
        const int cur = kt & 1;
        // issue next tile's loads now; they stay in flight across BOTH
        // lgkm-only barriers and drain at the end-of-iter __syncthreads.
        if (kt + 1 < NT) stage(kt + 1, cur ^ 1);

        // S = Q K^T: 2 m-blocks x own 16 keys; ONE K read feeds 2 MFMAs
        f32x4 sacc[2];
        sacc[0] = (f32x4){0.f,0.f,0.f,0.f};
        sacc[1] = (f32x4){0.f,0.f,0.f,0.f};
        #pragma unroll
        for (int t = 0; t < 16; ++t) {
            bf16x8 kb = *reinterpret_cast<const bf16x8*>(
                &Ks[cur][kh*16 + lr][(((t<<2)|quad) ^ kxor) << 3]);
            sacc[0] = __builtin_amdgcn_mfma_f32_16x16x32_bf16(qf[0][t], kb, sacc[0], 0, 0, 0);
            sacc[1] = __builtin_amdgcn_mfma_f32_16x16x32_bf16(qf[1][t], kb, sacc[1], 0, 0, 0);
        }

        // local 16-lane max per row; post onto exchange buffer
        float mx[2][4];
        #pragma unroll
        for (int mb = 0; mb < 2; ++mb)
            #pragma unroll
            for (int r = 0; r < 4; ++r) {
                float m = sacc[mb][r];
                #pragma unroll
                for (int off = 1; off < 16; off <<= 1)
                    m = fmaxf(m, __shfl_xor(m, off));
                mx[mb][r] = m;
            }
        if (lr == 0) {
            #pragma unroll
            for (int mb = 0; mb < 2; ++mb)
                #pragma unroll
                for (int r = 0; r < 4; ++r)
                    Sm[qg][kh][mb*16 + quad*4 + r] = mx[mb][r];
        }
        LGKM_BARRIER();   // #1: Sm visible (vmcnt untouched)

        // joint max, alpha, P, per-half l
        float alpha[2][4];
        #pragma unroll
        for (int mb = 0; mb < 2; ++mb)
            #pragma unroll
            for (int r = 0; r < 4; ++r) {
                float pm   = Sm[qg][kh ^ 1][mb*16 + quad*4 + r];
                float mnew = fmaxf(m_run[mb][r], fmaxf(mx[mb][r], pm));
                alpha[mb][r] = __expf(m_run[mb][r] - mnew);
                float p    = __expf(sacc[mb][r] - mnew);
                m_run[mb][r] = mnew;
                Ps[qg][mb*16 + quad*4 + r][kh*16 + lr] = f_to_bf16(p);
                float rs = p;
                #pragma unroll
                for (int off = 1; off < 16; off <<= 1)
                    rs += __shfl_xor(rs, off);
                l_run[mb][r] = l_run[mb][r]*alpha[mb][r] + rs;
            }
        // skip O-rescale when every alpha is exactly 1.0 (bit-exact skip)
        bool need = !(alpha[0][0]==1.f && alpha[0][1]==1.f && alpha[0][2]==1.f && alpha[0][3]==1.f &&
                      alpha[1][0]==1.f && alpha[1][1]==1.f && alpha[1][2]==1.f && alpha[1][3]==1.f);
        if (__any(need)) {
            #pragma unroll
            for (int mb = 0; mb < 2; ++mb)
                #pragma unroll
                for (int n = 0; n < 16; ++n)
                    #pragma unroll
                    for (int r = 0; r < 4; ++r) o[mb][n][r] *= alpha[mb][r];
        }
        LGKM_BARRIER();   // #2: full Ps tile visible (vmcnt untouched)

        // P fragments: A[m=lr][k=quad*8+j], full 32 keys, one per m-block
        bf16x8 pa0 = *reinterpret_cast<const bf16x8*>(&Ps[qg][lr][quad*8]);
        bf16x8 pa1 = *reinterpret_cast<const bf16x8*>(&Ps[qg][16 + lr][quad*8]);

        // PV: own 16 d-blocks (d = kh*256 ..); ONE V read feeds 2 MFMAs
        #pragma unroll
        for (int n = 0; n < 16; ++n) {
            int dblk = kh*16 + n;
            bf16x8 vb = *reinterpret_cast<const bf16x8*>(
                &Vt[cur][dblk*16 + lr][(quad ^ vxor) << 3]);
            o[0][n] = __builtin_amdgcn_mfma_f32_16x16x32_bf16(pa0, vb, o[0][n], 0, 0, 0);
            o[1][n] = __builtin_amdgcn_mfma_f32_16x16x32_bf16(pa1, vb, o[1][n], 0, 0, 0);
        }

        // single full barrier per iter: drains vmcnt (next tile resident)
        // and closes this iter's LDS reads before buffers are reused.
        __syncthreads();
    }

    // final l = own half + partner half (alpha sequence was shared)
    if (lr == 0) {
        #pragma unroll
        for (int mb = 0; mb < 2; ++mb)
            #pragma unroll
            for (int r = 0; r < 4; ++r)
                Sm[qg][kh][mb*16 + quad*4 + r] = l_run[mb][r];
    }
    __syncthreads();
    #pragma unroll
    for (int mb = 0; mb < 2; ++mb)
        #pragma unroll
        for (int r = 0; r < 4; ++r) {
            float l_tot = l_run[mb][r] + Sm[qg][kh ^ 1][mb*16 + quad*4 + r];
            float inv   = 1.0f / l_tot;
            int row = q0 + qg*32 + mb*16 + quad*4 + r;
            float* obase = out + ((size_t)bb * SEQ + row) * D_MODEL;
            #pragma unroll
            for (int n = 0; n < 16; ++n)
                obase[(kh*16 + n)*16 + lr] = o[mb][n][r] * inv;
        }
}

extern "C" void kernel_launch(void* const* d_in, const int* in_sizes, int n_in,
                              void* d_out, int out_size, void* d_ws, size_t ws_size,
                              hipStream_t stream) {
    const float* x = (const float*)d_in[0];
    const float* w = (const float*)d_in[1];
    const float* b = (const float*)d_in[2];
    float* out = (float*)d_out;
    unsigned short* node_bf  = (unsigned short*)d_ws;
    unsigned short* nodeT_bf = node_bf + (size_t)M_TOT * D_MODEL;
    const size_t out_bytes = (size_t)out_size * 4;

    // canary: if nothing below writes d_out, absmax ~= 48.6
    (void)hipMemsetAsync(d_out, 0x42, out_bytes, stream);

    if (d_ws == 0 || ws_size < WS_NEEDED) {
        (void)hipMemsetAsync(d_out, 0x4F, out_bytes, stream);   // ws sentinel
        return;
    }

    (void)hipGetLastError();
    proj_kernel<<<dim3(M_TOT/64, D_MODEL/64), dim3(256), 0, stream>>>(x, w, b, node_bf, nodeT_bf);
    hipError_t ep = hipGetLastError();
    flash_kernel<<<dim3(SEQ/64, BATCH), dim3(256), 0, stream>>>(node_bf, nodeT_bf, out);
    hipError_t ef = hipGetLastError();

    if (ep != hipSuccess) {
        (void)hipMemsetAsync(d_out, 0x49, out_bytes, stream);   // proj launch fail
    } else if (ef != hipSuccess) {
        (void)hipMemsetAsync(d_out, 0x4B, out_bytes, stream);   // flash launch fail
    }
}

// Round 4
// 530.052 us; speedup vs baseline: 1.4149x; 1.4149x over previous
//
#include <hip/hip_runtime.h>

#define D_MODEL 512
#define SEQ     4096
#define BATCH   4
#define M_TOT   (BATCH*SEQ)   // 16384
#define NT      (SEQ/32)      // 128 key tiles
#define WS_NEEDED ((size_t)2 * M_TOT * D_MODEL * 2)   // node_bf + nodeT_bf: 32 MiB

typedef float  f32x4  __attribute__((ext_vector_type(4)));
typedef __bf16 bf16x8 __attribute__((ext_vector_type(8)));

// lgkm-only barrier: syncs LDS data across waves WITHOUT draining vmcnt,
// so in-flight global_load_lds prefetches survive across it.
#define LGKM_BARRIER() asm volatile("s_waitcnt lgkmcnt(0)\n\ts_barrier" ::: "memory")

union FU { float f; unsigned int u; };
__device__ __forceinline__ unsigned short f_to_bf16(float f) {
    FU c; c.f = f;
    unsigned int r = c.u + 0x7fffu + ((c.u >> 16) & 1u);   // RNE
    return (unsigned short)(r >> 16);
}

// ---- DPP cross-lane (VALU pipe, NOT the DS pipe like __shfl_xor) ----
// 16-lane butterfly: quad_perm(1,0,3,2)=xor1, quad_perm(2,3,0,1)=xor2,
// row_half_mirror(0x141) ≡ xor4 after the first two stages,
// row_mirror(0x140)      ≡ xor8 after the first three.
// Operand pairings are commutative-identical to shfl_xor(1,2,4,8):
// results are BITWISE identical to the old tree.
template<int CTRL>
__device__ __forceinline__ float dpp_mov(float x) {
    union { float f; int i; } u, r;
    u.f = x;
    r.i = __builtin_amdgcn_update_dpp(u.i, u.i, CTRL, 0xF, 0xF, false);
    return r.f;
}
__device__ __forceinline__ float red_max16(float x) {
    x = fmaxf(x, dpp_mov<0xB1>(x));
    x = fmaxf(x, dpp_mov<0x4E>(x));
    x = fmaxf(x, dpp_mov<0x141>(x));
    x = fmaxf(x, dpp_mov<0x140>(x));
    return x;
}
__device__ __forceinline__ float red_sum16(float x) {
    x += dpp_mov<0xB1>(x);
    x += dpp_mov<0x4E>(x);
    x += dpp_mov<0x141>(x);
    x += dpp_mov<0x140>(x);
    return x;
}

// -------- K1: node_bf = relu(x @ W^T + b) (bf16), + transposed copy --------
extern "C" __global__ __launch_bounds__(256) void proj_kernel(
        const float* __restrict__ x, const float* __restrict__ w,
        const float* __restrict__ bias,
        unsigned short* __restrict__ node_bf, unsigned short* __restrict__ nodeT_bf) {
    __shared__ float As[32][68];   // k-major, +4 pad
    __shared__ float Bs[32][68];
    const int tid  = threadIdx.x;
    const int row0 = blockIdx.x * 64;
    const int col0 = blockIdx.y * 64;
    const int m0   = (tid & 15) * 4;
    const int n0   = (tid >> 4) * 4;

    float acc[4][4];
    #pragma unroll
    for (int i = 0; i < 4; ++i)
        #pragma unroll
        for (int j = 0; j < 4; ++j) acc[i][j] = 0.0f;

    for (int kc = 0; kc < D_MODEL; kc += 32) {
        #pragma unroll
        for (int jj = 0; jj < 2; ++jj) {
            int fi = tid + 256*jj;
            int r  = fi >> 3, c4 = (fi & 7) * 4;
            float4 a4 = *(const float4*)(x + (size_t)(row0 + r)*D_MODEL + kc + c4);
            As[c4+0][r] = a4.x; As[c4+1][r] = a4.y; As[c4+2][r] = a4.z; As[c4+3][r] = a4.w;
            float4 b4 = *(const float4*)(w + (size_t)(col0 + r)*D_MODEL + kc + c4);
            Bs[c4+0][r] = b4.x; Bs[c4+1][r] = b4.y; Bs[c4+2][r] = b4.z; Bs[c4+3][r] = b4.w;
        }
        __syncthreads();
        #pragma unroll
        for (int k = 0; k < 32; ++k) {
            float4 a = *(const float4*)&As[k][m0];
            float4 b = *(const float4*)&Bs[k][n0];
            acc[0][0] += a.x*b.x; acc[0][1] += a.x*b.y; acc[0][2] += a.x*b.z; acc[0][3] += a.x*b.w;
            acc[1][0] += a.y*b.x; acc[1][1] += a.y*b.y; acc[1][2] += a.y*b.z; acc[1][3] += a.y*b.w;
            acc[2][0] += a.z*b.x; acc[2][1] += a.z*b.y; acc[2][2] += a.z*b.z; acc[2][3] += a.z*b.w;
            acc[3][0] += a.w*b.x; acc[3][1] += a.w*b.y; acc[3][2] += a.w*b.z; acc[3][3] += a.w*b.w;
        }
        __syncthreads();
    }
    #pragma unroll
    for (int j = 0; j < 4; ++j) {
        float bv = bias[col0 + n0 + j];
        #pragma unroll
        for (int i = 0; i < 4; ++i) {
            float v = acc[i][j] + bv;
            v = v > 0.0f ? v : 0.0f;
            unsigned short us = f_to_bf16(v);
            int row = row0 + m0 + i, col = col0 + n0 + j;
            node_bf[(size_t)row*D_MODEL + col] = us;
            int b = row >> 12, si = row & 4095;
            nodeT_bf[((size_t)(b*D_MODEL + col))*SEQ + si] = us;
        }
    }
}

// -------- K2: flash attention via MFMA, out(fp32) --------
// v5 = v3 (proven best) + DPP softmax reductions (DS pipe -> VALU pipe,
// bitwise-identical pairings) + s_setprio(1) around MFMA clusters (T5:
// 2 waves/SIMD at skewed phases is the regime where it pays).
// 8 waves/block (2 waves/SIMD). Wave (qg=w&3, kh=w>>2):
//   QK^T: its 16-key half (16 MFMA); joint row-max via 512B LDS exchange.
//   PV:   its 256-d half (16 MFMA) with the FULL 32-key P (no O merge).
//   l accumulated per-half with shared alpha; summed once at the end.
// Mid-iter barriers are lgkm-only (vmcnt NOT drained) so the top-of-iter
// global_load_lds prefetch spans the whole iteration, drained at the
// single end-of-iter __syncthreads().
// K chunk-swizzle: 16B chunk ^ (row&7); V chunk-swizzle: 16B chunk ^ (d&3)
// (both applied on the global SOURCE address, LDS dest linear — T21).
// LDS: 65536 (Ks) + 65536 (Vt) + 5120 (Ps) + 512 (Sm) = 136704 B
extern "C" __global__ __launch_bounds__(512, 2) void flash_kernel(
        const unsigned short* __restrict__ node,
        const unsigned short* __restrict__ nodeT,
        float* __restrict__ out) {
    __shared__ unsigned short Ks[2][32][512];   // [buf][key][d]
    __shared__ unsigned short Vt[2][512][32];   // [buf][d][key]
    __shared__ unsigned short Ps[4][16][40];    // [qg][qrow][key], +8 pad
    __shared__ float          Sm[4][2][16];     // [qg][kh][row] exchange buffer
    const int tid  = threadIdx.x;
    const int lane = tid & 63;
    const int wv   = tid >> 6;        // 0..7
    const int qg   = wv & 3;          // qrow group
    const int kh   = wv >> 2;         // key half (QK) / d half (PV)
    const int lr   = lane & 15;
    const int quad = lane >> 4;
    const int bb   = blockIdx.y;
    const int q0   = blockIdx.x * 64;

    const unsigned short* nb  = node  + (size_t)bb * SEQ * D_MODEL;
    const unsigned short* ntb = nodeT + (size_t)bb * D_MODEL * SEQ;

    // Q fragments: A[m=lr][k = t*32 + quad*8 + j]
    bf16x8 qf[16];
    const int qrow = q0 + qg*16 + lr;
    #pragma unroll
    for (int t = 0; t < 16; ++t)
        qf[t] = *reinterpret_cast<const bf16x8*>(&nb[(size_t)qrow*D_MODEL + t*32 + quad*8]);

    f32x4 o[16];                      // 16 qrows x 256 d (own half)
    #pragma unroll
    for (int n = 0; n < 16; ++n) o[n] = (f32x4){0.f,0.f,0.f,0.f};
    float m_run[4] = {-3.0e38f,-3.0e38f,-3.0e38f,-3.0e38f};
    float l_run[4] = {0.f,0.f,0.f,0.f};

    // stage tile kt into buffer buf; work split across all 8 waves:
    // each wave: 4 K rows (1 KiB each) + 4 V chunks (16 d-rows each).
    auto stage = [&](int kt, int buf) {
        #pragma unroll
        for (int i = 0; i < 4; ++i) {
            int r = wv*4 + i;
            const unsigned short* g = nb + (size_t)(kt*32 + r)*D_MODEL + ((lane ^ (r & 7)) << 3);
            __builtin_amdgcn_global_load_lds(
                (const __attribute__((address_space(1))) unsigned int*)g,
                (__attribute__((address_space(3))) unsigned int*)&Ks[buf][r][0],
                16, 0, 0);
        }
        #pragma unroll
        for (int i = 0; i < 4; ++i) {
            int d0 = (wv*4 + i) * 16;
            int d  = d0 + (lane >> 2);
            const unsigned short* g = ntb + (size_t)d*SEQ + kt*32 + ((((lane & 3) ^ (d & 3))) << 3);
            __builtin_amdgcn_global_load_lds(
                (const __attribute__((address_space(1))) unsigned int*)g,
                (__attribute__((address_space(3))) unsigned int*)&Vt[buf][d0][0],
                16, 0, 0);
        }
    };

    stage(0, 0);
    __syncthreads();           // drains vmcnt: tile 0 resident

    const int kxor = lr & 7;   // K read swizzle ((kh*16+lr)&7 == lr&7)
    const int vxor = lr & 3;   // V read swizzle ((dblk*16+lr)&3 == lr&3)

    for (int kt = 0; kt < NT; ++kt) {
        const int cur = kt & 1;
        // issue next tile's loads now; they stay in flight across BOTH
        // lgkm-only barriers and drain at the end-of-iter __syncthreads.
        if (kt + 1 < NT) stage(kt + 1, cur ^ 1);

        // S half = Q K^T (16 qrows x own 16 keys); swizzled K read
        f32x4 sacc = (f32x4){0.f,0.f,0.f,0.f};
        __builtin_amdgcn_s_setprio(1);
        #pragma unroll
        for (int t = 0; t < 16; ++t) {
            bf16x8 kb = *reinterpret_cast<const bf16x8*>(
                &Ks[cur][kh*16 + lr][(((t<<2)|quad) ^ kxor) << 3]);
            sacc = __builtin_amdgcn_mfma_f32_16x16x32_bf16(qf[t], kb, sacc, 0, 0, 0);
        }
        __builtin_amdgcn_s_setprio(0);

        // local 16-lane max per row (DPP tree, VALU pipe); post to exchange
        float mx[4];
        #pragma unroll
        for (int r = 0; r < 4; ++r) mx[r] = red_max16(sacc[r]);
        if (lr == 0) {
            #pragma unroll
            for (int r = 0; r < 4; ++r) Sm[qg][kh][quad*4 + r] = mx[r];
        }
        LGKM_BARRIER();   // #1: Sm visible (vmcnt untouched)

        // joint max, alpha, P, per-half l (sum tree also DPP)
        float alpha[4];
        #pragma unroll
        for (int r = 0; r < 4; ++r) {
            float pm   = Sm[qg][kh ^ 1][quad*4 + r];
            float mnew = fmaxf(m_run[r], fmaxf(mx[r], pm));
            alpha[r]   = __expf(m_run[r] - mnew);
            float p    = __expf(sacc[r] - mnew);
            m_run[r]   = mnew;
            Ps[qg][quad*4 + r][kh*16 + lr] = f_to_bf16(p);
            float rs   = red_sum16(p);
            l_run[r] = l_run[r]*alpha[r] + rs;
        }
        // skip O-rescale when every alpha is exactly 1.0 (bit-exact skip)
        bool need = !(alpha[0]==1.f && alpha[1]==1.f && alpha[2]==1.f && alpha[3]==1.f);
        if (__any(need)) {
            #pragma unroll
            for (int n = 0; n < 16; ++n) {
                #pragma unroll
                for (int r = 0; r < 4; ++r) o[n][r] *= alpha[r];
            }
        }
        LGKM_BARRIER();   // #2: full Ps tile visible (vmcnt untouched)

        // P fragment: A[m=lr][k=quad*8+j], full 32 keys
        bf16x8 pa = *reinterpret_cast<const bf16x8*>(&Ps[qg][lr][quad*8]);

        // PV: own 16 d-blocks (d = kh*256 .. kh*256+255), swizzled V read
        __builtin_amdgcn_s_setprio(1);
        #pragma unroll
        for (int n = 0; n < 16; ++n) {
            int dblk = kh*16 + n;
            bf16x8 vb = *reinterpret_cast<const bf16x8*>(
                &Vt[cur][dblk*16 + lr][(quad ^ vxor) << 3]);
            o[n] = __builtin_amdgcn_mfma_f32_16x16x32_bf16(pa, vb, o[n], 0, 0, 0);
        }
        __builtin_amdgcn_s_setprio(0);

        // single full barrier per iter: drains vmcnt (next tile resident)
        // and closes this iter's LDS reads before buffers are reused.
        __syncthreads();
    }

    // final l = own half + partner half (alpha sequence was shared)
    if (lr == 0) {
        #pragma unroll
        for (int r = 0; r < 4; ++r) Sm[qg][kh][quad*4 + r] = l_run[r];
    }
    __syncthreads();
    #pragma unroll
    for (int r = 0; r < 4; ++r) {
        float l_tot = l_run[r] + Sm[qg][kh ^ 1][quad*4 + r];
        float inv   = 1.0f / l_tot;
        int row = q0 + qg*16 + quad*4 + r;
        float* obase = out + ((size_t)bb * SEQ + row) * D_MODEL;
        #pragma unroll
        for (int n = 0; n < 16; ++n)
            obase[(kh*16 + n)*16 + lr] = o[n][r] * inv;
    }
}

extern "C" void kernel_launch(void* const* d_in, const int* in_sizes, int n_in,
                              void* d_out, int out_size, void* d_ws, size_t ws_size,
                              hipStream_t stream) {
    const float* x = (const float*)d_in[0];
    const float* w = (const float*)d_in[1];
    const float* b = (const float*)d_in[2];
    float* out = (float*)d_out;
    unsigned short* node_bf  = (unsigned short*)d_ws;
    unsigned short* nodeT_bf = node_bf + (size_t)M_TOT * D_MODEL;
    const size_t out_bytes = (size_t)out_size * 4;

    // canary: if nothing below writes d_out, absmax ~= 48.6
    (void)hipMemsetAsync(d_out, 0x42, out_bytes, stream);

    if (d_ws == 0 || ws_size < WS_NEEDED) {
        (void)hipMemsetAsync(d_out, 0x4F, out_bytes, stream);   // ws sentinel
        return;
    }

    (void)hipGetLastError();
    proj_kernel<<<dim3(M_TOT/64, D_MODEL/64), dim3(256), 0, stream>>>(x, w, b, node_bf, nodeT_bf);
    hipError_t ep = hipGetLastError();
    flash_kernel<<<dim3(SEQ/64, BATCH), dim3(512), 0, stream>>>(node_bf, nodeT_bf, out);
    hipError_t ef = hipGetLastError();

    if (ep != hipSuccess) {
        (void)hipMemsetAsync(d_out, 0x49, out_bytes, stream);   // proj launch fail
    } else if (ef != hipSuccess) {
        (void)hipMemsetAsync(d_out, 0x4B, out_bytes, stream);   // flash launch fail
    }
}

// Round 6
// 458.351 us; speedup vs baseline: 1.6363x; 1.1564x over previous
//
#include <hip/hip_runtime.h>

#define D_MODEL 512
#define SEQ     4096
#define BATCH   4
#define M_TOT   (BATCH*SEQ)   // 16384
#define NT      (SEQ/32)      // 128 key tiles
#define WS_NEEDED ((size_t)2 * M_TOT * D_MODEL * 2)   // node_bf + nodeT_bf: 32 MiB

typedef float  f32x4  __attribute__((ext_vector_type(4)));
typedef __bf16 bf16x8 __attribute__((ext_vector_type(8)));

// lgkm-only barrier: syncs LDS data across waves WITHOUT draining vmcnt,
// so in-flight global_load_lds prefetches survive across it.
#define LGKM_BARRIER() asm volatile("s_waitcnt lgkmcnt(0)\n\ts_barrier" ::: "memory")

union FU { float f; unsigned int u; };
__device__ __forceinline__ unsigned short f_to_bf16(float f) {
    FU c; c.f = f;
    unsigned int r = c.u + 0x7fffu + ((c.u >> 16) & 1u);   // RNE
    return (unsigned short)(r >> 16);
}

// split fp32 pair -> packed hi (truncated top16) + packed lo (RNE bf16 of
// exact residual). hi+lo reproduces x to ~2^-17 relative.
__device__ __forceinline__ void split_pack(float f0, float f1,
        unsigned int& hp, unsigned int& lp) {
    FU u0, u1; u0.f = f0; u1.f = f1;
    unsigned int h0 = u0.u & 0xFFFF0000u, h1 = u1.u & 0xFFFF0000u;
    hp = (h0 >> 16) | h1;
    FU t0, t1; t0.u = h0; t1.u = h1;
    float l0 = f0 - t0.f, l1 = f1 - t1.f;       // exact (Sterbenz)
    lp = (unsigned)f_to_bf16(l0) | ((unsigned)f_to_bf16(l1) << 16);
}

// ---- DPP cross-lane (VALU pipe, NOT the DS pipe like __shfl_xor) ----
// 16-lane butterfly, pairings commutative-identical to shfl_xor(1,2,4,8):
// results BITWISE identical to a shfl tree.
template<int CTRL>
__device__ __forceinline__ float dpp_mov(float x) {
    union { float f; int i; } u, r;
    u.f = x;
    r.i = __builtin_amdgcn_update_dpp(u.i, u.i, CTRL, 0xF, 0xF, false);
    return r.f;
}
__device__ __forceinline__ float red_max16(float x) {
    x = fmaxf(x, dpp_mov<0xB1>(x));
    x = fmaxf(x, dpp_mov<0x4E>(x));
    x = fmaxf(x, dpp_mov<0x141>(x));
    x = fmaxf(x, dpp_mov<0x140>(x));
    return x;
}
__device__ __forceinline__ float red_sum16(float x) {
    x += dpp_mov<0xB1>(x);
    x += dpp_mov<0x4E>(x);
    x += dpp_mov<0x141>(x);
    x += dpp_mov<0x140>(x);
    return x;
}

// -------- K1: node_bf = relu(x @ W^T + b) (bf16), + transposed copy --------
// v7: split-bf16 MFMA GEMM. x = x_hi + x_lo, W = W_hi + W_lo (hi = trunc
// top-16, lo = RNE(residual)); x@W^T = hi*hi + hi*lo + lo*hi via 3 bf16
// MFMAs, fp32 accum (lo*lo ~2^-16 rel, dropped). Output only ever consumed
// as bf16 -> node_bf bits match the fp32 pipeline except ~<<1% boundary
// cases (1 bf16 ulp). Replaces 173us of fp32 vector-ALU GEMM with ~26 GF
// of MFMA work. Tile 128x128, 4 waves (2x2), 16 k-steps, single-buffered.
// LDS: 4 tiles x [128][40] bf16 = 40960 B. Stride 40 elems = 80 B: 16B
// aligned for b128, bank stride 20 -> <=2-way (free, m136).
extern "C" __global__ __launch_bounds__(256, 2) void proj_kernel(
        const float* __restrict__ x, const float* __restrict__ w,
        const float* __restrict__ bias,
        unsigned short* __restrict__ node_bf, unsigned short* __restrict__ nodeT_bf) {
    __shared__ unsigned short Ah[128][40], Al[128][40], Bh[128][40], Bl[128][40];
    const int tid  = threadIdx.x;
    const int lane = tid & 63;
    const int wv   = tid >> 6;        // 0..3
    const int lr   = lane & 15;
    const int quad = lane >> 4;
    const int row0 = blockIdx.x * 128;
    const int col0 = blockIdx.y * 128;
    const int wm   = (wv & 1) * 64;
    const int wn   = (wv >> 1) * 64;

    f32x4 acc[4][4];
    #pragma unroll
    for (int i = 0; i < 4; ++i)
        #pragma unroll
        for (int j = 0; j < 4; ++j) acc[i][j] = (f32x4){0.f,0.f,0.f,0.f};

    for (int kc = 0; kc < D_MODEL; kc += 32) {
        // stage + split: tile = 128 rows x 32 k. 512 chunks of 8 elems;
        // thread handles 2 chunks for x and 2 for w.
        #pragma unroll
        for (int i = 0; i < 2; ++i) {
            int idx = i*256 + tid;
            int r = idx >> 2, c8 = (idx & 3) * 8;
            const float* xp = x + (size_t)(row0 + r)*D_MODEL + kc + c8;
            const float* wp = w + (size_t)(col0 + r)*D_MODEL + kc + c8;
            float4 a0 = *(const float4*)(xp);
            float4 a1 = *(const float4*)(xp + 4);
            float4 b0 = *(const float4*)(wp);
            float4 b1 = *(const float4*)(wp + 4);
            uint4 hA, lA, hB, lB;
            split_pack(a0.x, a0.y, hA.x, lA.x);
            split_pack(a0.z, a0.w, hA.y, lA.y);
            split_pack(a1.x, a1.y, hA.z, lA.z);
            split_pack(a1.z, a1.w, hA.w, lA.w);
            split_pack(b0.x, b0.y, hB.x, lB.x);
            split_pack(b0.z, b0.w, hB.y, lB.y);
            split_pack(b1.x, b1.y, hB.z, lB.z);
            split_pack(b1.z, b1.w, hB.w, lB.w);
            *(uint4*)&Ah[r][c8] = hA;
            *(uint4*)&Al[r][c8] = lA;
            *(uint4*)&Bh[r][c8] = hB;
            *(uint4*)&Bl[r][c8] = lB;
        }
        __syncthreads();

        bf16x8 ah[4], al[4], bh[4], bl[4];
        #pragma unroll
        for (int i = 0; i < 4; ++i) {
            ah[i] = *(const bf16x8*)&Ah[wm + i*16 + lr][quad*8];
            al[i] = *(const bf16x8*)&Al[wm + i*16 + lr][quad*8];
            bh[i] = *(const bf16x8*)&Bh[wn + i*16 + lr][quad*8];
            bl[i] = *(const bf16x8*)&Bl[wn + i*16 + lr][quad*8];
        }
        #pragma unroll
        for (int i = 0; i < 4; ++i)
            #pragma unroll
            for (int j = 0; j < 4; ++j) {
                acc[i][j] = __builtin_amdgcn_mfma_f32_16x16x32_bf16(al[i], bh[j], acc[i][j], 0, 0, 0);
                acc[i][j] = __builtin_amdgcn_mfma_f32_16x16x32_bf16(ah[i], bl[j], acc[i][j], 0, 0, 0);
                acc[i][j] = __builtin_amdgcn_mfma_f32_16x16x32_bf16(ah[i], bh[j], acc[i][j], 0, 0, 0);
            }
        __syncthreads();
    }

    // epilogue: +bias, relu, RNE->bf16, write node + transposed copy.
    // C/D layout (m89): row = quad*4 + r, col = lr.
    #pragma unroll
    for (int j = 0; j < 4; ++j) {
        int col = col0 + wn + j*16 + lr;
        float bv = bias[col];
        #pragma unroll
        for (int i = 0; i < 4; ++i) {
            #pragma unroll
            for (int r = 0; r < 4; ++r) {
                float v = acc[i][j][r] + bv;
                v = v > 0.0f ? v : 0.0f;
                unsigned short us = f_to_bf16(v);
                int row = row0 + wm + i*16 + quad*4 + r;
                node_bf[(size_t)row*D_MODEL + col] = us;
                int b = row >> 12, si = row & 4095;
                nodeT_bf[((size_t)(b*D_MODEL + col))*SEQ + si] = us;
            }
        }
    }
}

// -------- K2: flash attention via MFMA, out(fp32) --------
// v5 (PROVEN, 357us, reverted from failed v6): 8 waves/block, DPP softmax,
// setprio around MFMA clusters, double-buffered K+V via global_load_lds
// (linear dest + source swizzle, T21), lgkm-only mid-iter barriers, single
// vmcnt-draining __syncthreads per iter.
// LDS: 65536 (Ks) + 65536 (Vt) + 5120 (Ps) + 512 (Sm) = 136704 B
extern "C" __global__ __launch_bounds__(512, 2) void flash_kernel(
        const unsigned short* __restrict__ node,
        const unsigned short* __restrict__ nodeT,
        float* __restrict__ out) {
    __shared__ unsigned short Ks[2][32][512];   // [buf][key][d]
    __shared__ unsigned short Vt[2][512][32];   // [buf][d][key]
    __shared__ unsigned short Ps[4][16][40];    // [qg][qrow][key], +8 pad
    __shared__ float          Sm[4][2][16];     // [qg][kh][row] exchange buffer
    const int tid  = threadIdx.x;
    const int lane = tid & 63;
    const int wv   = tid >> 6;        // 0..7
    const int qg   = wv & 3;          // qrow group
    const int kh   = wv >> 2;         // key half (QK) / d half (PV)
    const int lr   = lane & 15;
    const int quad = lane >> 4;
    const int bb   = blockIdx.y;
    const int q0   = blockIdx.x * 64;

    const unsigned short* nb  = node  + (size_t)bb * SEQ * D_MODEL;
    const unsigned short* ntb = nodeT + (size_t)bb * D_MODEL * SEQ;

    // Q fragments: A[m=lr][k = t*32 + quad*8 + j]
    bf16x8 qf[16];
    const int qrow = q0 + qg*16 + lr;
    #pragma unroll
    for (int t = 0; t < 16; ++t)
        qf[t] = *reinterpret_cast<const bf16x8*>(&nb[(size_t)qrow*D_MODEL + t*32 + quad*8]);

    f32x4 o[16];                      // 16 qrows x 256 d (own half)
    #pragma unroll
    for (int n = 0; n < 16; ++n) o[n] = (f32x4){0.f,0.f,0.f,0.f};
    float m_run[4] = {-3.0e38f,-3.0e38f,-3.0e38f,-3.0e38f};
    float l_run[4] = {0.f,0.f,0.f,0.f};

    // stage tile kt into buffer buf; work split across all 8 waves:
    // each wave: 4 K rows (1 KiB each) + 4 V chunks (16 d-rows each).
    auto stage = [&](int kt, int buf) {
        #pragma unroll
        for (int i = 0; i < 4; ++i) {
            int r = wv*4 + i;
            const unsigned short* g = nb + (size_t)(kt*32 + r)*D_MODEL + ((lane ^ (r & 7)) << 3);
            __builtin_amdgcn_global_load_lds(
                (const __attribute__((address_space(1))) unsigned int*)g,
                (__attribute__((address_space(3))) unsigned int*)&Ks[buf][r][0],
                16, 0, 0);
        }
        #pragma unroll
        for (int i = 0; i < 4; ++i) {
            int d0 = (wv*4 + i) * 16;
            int d  = d0 + (lane >> 2);
            const unsigned short* g = ntb + (size_t)d*SEQ + kt*32 + ((((lane & 3) ^ (d & 3))) << 3);
            __builtin_amdgcn_global_load_lds(
                (const __attribute__((address_space(1))) unsigned int*)g,
                (__attribute__((address_space(3))) unsigned int*)&Vt[buf][d0][0],
                16, 0, 0);
        }
    };

    stage(0, 0);
    __syncthreads();           // drains vmcnt: tile 0 resident

    const int kxor = lr & 7;   // K read swizzle ((kh*16+lr)&7 == lr&7)
    const int vxor = lr & 3;   // V read swizzle ((dblk*16+lr)&3 == lr&3)

    for (int kt = 0; kt < NT; ++kt) {
        const int cur = kt & 1;
        // issue next tile's loads now; they stay in flight across BOTH
        // lgkm-only barriers and drain at the end-of-iter __syncthreads.
        if (kt + 1 < NT) stage(kt + 1, cur ^ 1);

        // S half = Q K^T (16 qrows x own 16 keys); swizzled K read
        f32x4 sacc = (f32x4){0.f,0.f,0.f,0.f};
        __builtin_amdgcn_s_setprio(1);
        #pragma unroll
        for (int t = 0; t < 16; ++t) {
            bf16x8 kb = *reinterpret_cast<const bf16x8*>(
                &Ks[cur][kh*16 + lr][(((t<<2)|quad) ^ kxor) << 3]);
            sacc = __builtin_amdgcn_mfma_f32_16x16x32_bf16(qf[t], kb, sacc, 0, 0, 0);
        }
        __builtin_amdgcn_s_setprio(0);

        // local 16-lane max per row (DPP tree, VALU pipe); post to exchange
        float mx[4];
        #pragma unroll
        for (int r = 0; r < 4; ++r) mx[r] = red_max16(sacc[r]);
        if (lr == 0) {
            #pragma unroll
            for (int r = 0; r < 4; ++r) Sm[qg][kh][quad*4 + r] = mx[r];
        }
        LGKM_BARRIER();   // #1: Sm visible (vmcnt untouched)

        // joint max, alpha, P, per-half l (sum tree also DPP)
        float alpha[4];
        #pragma unroll
        for (int r = 0; r < 4; ++r) {
            float pm   = Sm[qg][kh ^ 1][quad*4 + r];
            float mnew = fmaxf(m_run[r], fmaxf(mx[r], pm));
            alpha[r]   = __expf(m_run[r] - mnew);
            float p    = __expf(sacc[r] - mnew);
            m_run[r]   = mnew;
            Ps[qg][quad*4 + r][kh*16 + lr] = f_to_bf16(p);
            float rs   = red_sum16(p);
            l_run[r] = l_run[r]*alpha[r] + rs;
        }
        // skip O-rescale when every alpha is exactly 1.0 (bit-exact skip)
        bool need = !(alpha[0]==1.f && alpha[1]==1.f && alpha[2]==1.f && alpha[3]==1.f);
        if (__any(need)) {
            #pragma unroll
            for (int n = 0; n < 16; ++n) {
                #pragma unroll
                for (int r = 0; r < 4; ++r) o[n][r] *= alpha[r];
            }
        }
        LGKM_BARRIER();   // #2: full Ps tile visible (vmcnt untouched)

        // P fragment: A[m=lr][k=quad*8+j], full 32 keys
        bf16x8 pa = *reinterpret_cast<const bf16x8*>(&Ps[qg][lr][quad*8]);

        // PV: own 16 d-blocks (d = kh*256 .. kh*256+255), swizzled V read
        __builtin_amdgcn_s_setprio(1);
        #pragma unroll
        for (int n = 0; n < 16; ++n) {
            int dblk = kh*16 + n;
            bf16x8 vb = *reinterpret_cast<const bf16x8*>(
                &Vt[cur][dblk*16 + lr][(quad ^ vxor) << 3]);
            o[n] = __builtin_amdgcn_mfma_f32_16x16x32_bf16(pa, vb, o[n], 0, 0, 0);
        }
        __builtin_amdgcn_s_setprio(0);

        // single full barrier per iter: drains vmcnt (next tile resident)
        // and closes this iter's LDS reads before buffers are reused.
        __syncthreads();
    }

    // final l = own half + partner half (alpha sequence was shared)
    if (lr == 0) {
        #pragma unroll
        for (int r = 0; r < 4; ++r) Sm[qg][kh][quad*4 + r] = l_run[r];
    }
    __syncthreads();
    #pragma unroll
    for (int r = 0; r < 4; ++r) {
        float l_tot = l_run[r] + Sm[qg][kh ^ 1][quad*4 + r];
        float inv   = 1.0f / l_tot;
        int row = q0 + qg*16 + quad*4 + r;
        float* obase = out + ((size_t)bb * SEQ + row) * D_MODEL;
        #pragma unroll
        for (int n = 0; n < 16; ++n)
            obase[(kh*16 + n)*16 + lr] = o[n][r] * inv;
    }
}

extern "C" void kernel_launch(void* const* d_in, const int* in_sizes, int n_in,
                              void* d_out, int out_size, void* d_ws, size_t ws_size,
                              hipStream_t stream) {
    const float* x = (const float*)d_in[0];
    const float* w = (const float*)d_in[1];
    const float* b = (const float*)d_in[2];
    float* out = (float*)d_out;
    unsigned short* node_bf  = (unsigned short*)d_ws;
    unsigned short* nodeT_bf = node_bf + (size_t)M_TOT * D_MODEL;
    const size_t out_bytes = (size_t)out_size * 4;

    // canary: if nothing below writes d_out, absmax ~= 48.6
    (void)hipMemsetAsync(d_out, 0x42, out_bytes, stream);

    if (d_ws == 0 || ws_size < WS_NEEDED) {
        (void)hipMemsetAsync(d_out, 0x4F, out_bytes, stream);   // ws sentinel
        return;
    }

    (void)hipGetLastError();
    proj_kernel<<<dim3(M_TOT/128, D_MODEL/128), dim3(256), 0, stream>>>(x, w, b, node_bf, nodeT_bf);
    hipError_t ep = hipGetLastError();
    flash_kernel<<<dim3(SEQ/64, BATCH), dim3(512), 0, stream>>>(node_bf, nodeT_bf, out);
    hipError_t ef = hipGetLastError();

    if (ep != hipSuccess) {
        (void)hipMemsetAsync(d_out, 0x49, out_bytes, stream);   // proj launch fail
    } else if (ef != hipSuccess) {
        (void)hipMemsetAsync(d_out, 0x4B, out_bytes, stream);   // flash launch fail
    }
}